// Round 18
// baseline (382.295 us; speedup 1.0000x reference)
//
#include <hip/hip_runtime.h>

// AttentionHead: B=16384, W=10, D=1024, K=V=64
// out[b,i,:] = softmax_j( min(k_i . q_j, tri) ) @ v    (scores row = key index)
//
// GEMM front-end: 3-term split-FP16 MFMA. x = xh + xl*2^-11, w = wh + wl*2^-11
// (residuals pre-scaled by 2^11 -> fp16 normal range). f64-dot epilogue; f32 out.
//
// Round-18: BK=128 (KCHUNKS=8). Doubles the contiguous MFMA run per phase
// (180/wave) and halves the per-chunk turnaround count (ds_write->barrier->
// ds_read refill, W-load warmup). Single-buffered 2-barrier structure (R7/R8
// showed dbuf+issue-early neutral; avoids prefetch-liveness spill).
// Numerics bit-identical to R14 (same MFMA sequence per accumulator).

#define D 1024
#define BM 80            // 8 batches of 10 rows per block
#define KCHUNKS 8        // 1024 / 128
#define BK 128
#define ASTR 136         // staged row stride in shorts (128 data + 8 pad)
#define APIECE 21760     // bytes per staged piece [80][ASTR]
#define KQSTR 133        // kq row stride (floats)
#define VSTR 65          // v row stride (floats), overlay
#define SCOFF 42560      // byte offset of score buffer
#define SMEMSZ 46080     // max(staging 43520, epilogue 42560+3520)
#define SCL 4.8828125e-4f   // 2^-11

typedef __attribute__((ext_vector_type(8))) _Float16 f16x8;
typedef __attribute__((ext_vector_type(4))) float f32x4;
typedef __attribute__((ext_vector_type(4))) unsigned short u16x4;

// --- kernel0: split wk|wq|wv into transposed fp16 2-piece Wt[n][k]
__global__ __launch_bounds__(256) void prep_w(const float* __restrict__ wk,
                                              const float* __restrict__ wq,
                                              const float* __restrict__ wv,
                                              unsigned short* __restrict__ wth,
                                              unsigned short* __restrict__ wtl) {
    int idx = blockIdx.x * 256 + threadIdx.x;   // idx = n*1024 + kk, n in [0,192)
    int n  = idx >> 10;
    int kk = idx & 1023;
    const float* src = (n < 64) ? wk : (n < 128) ? wq : wv;
    float w = src[kk * 64 + (n & 63)];
    _Float16 h = (_Float16)w;
    float r = (w - (float)h) * 2048.0f;         // pre-scaled residual
    _Float16 l = (_Float16)r;
    wth[idx] = __builtin_bit_cast(unsigned short, h);
    wtl[idx] = __builtin_bit_cast(unsigned short, l);
}

// --- kernel1: fused 3-term fp16 projection GEMM + attention
__global__ __launch_bounds__(256, 3) void fused_attn(
        const float* __restrict__ x,
        const unsigned short* __restrict__ wth,
        const unsigned short* __restrict__ wtl,
        float* __restrict__ out) {

    __shared__ char smem[SMEMSZ];
    unsigned short* AhS = (unsigned short*)smem;            // [80][ASTR] fp16 hi
    unsigned short* AlS = (unsigned short*)(smem + APIECE); // [80][ASTR] fp16 lo
    float* kq  = (float*)smem;                   // [80][KQSTR] = 42560 B
    float* vv  = (float*)smem;                   // [80][VSTR] overlay
    float* scw = (float*)(smem + SCOFF);         // [4][220] f32 probs

    const int tid  = threadIdx.x;
    const int wave = tid >> 6;
    const int lane = tid & 63;
    const int m0   = blockIdx.x * BM;
    const int nbase = wave * 48;          // 3 n-tiles of 16 per wave (192 total)
    const int arow  = lane & 15;
    const int apart = lane >> 4;          // 0..3

    // ---------- layout probe (register-only): acc (lane,reg) -> (row, col) ----
    f16x8 aprobe = {}, bone = {}, aone = {}, bcol = {};
    if (apart == 0) {
        aprobe[0] = (_Float16)(float)(arow + 1);  // A[m][0] = m+1
        bone[0]   = (_Float16)1.0f;               // B[0][n] = 1
        aone[0]   = (_Float16)1.0f;               // A[m][0] = 1
        bcol[0]   = (_Float16)(float)(arow + 1);  // B[0][n] = n+1
    }
    f32x4 z = {0.f, 0.f, 0.f, 0.f};
    f32x4 d1 = __builtin_amdgcn_mfma_f32_16x16x32_f16(aprobe, bone, z, 0, 0, 0); // row+1
    f32x4 d2 = __builtin_amdgcn_mfma_f32_16x16x32_f16(aone,  bcol, z, 0, 0, 0);  // col+1
    int R[4], Cc[4];
    #pragma unroll
    for (int r = 0; r < 4; ++r) {
        R[r]  = (int)(d1[r] + 0.5f) - 1;
        Cc[r] = (int)(d2[r] + 0.5f) - 1;
    }

    // ---------- GEMM: kqv[80][192] = x @ [wk|wq|wv], 3-term fp16 split -------
    f32x4 acc[5][3] = {};                 // 5 m-tiles x 3 n-tiles

    for (int t = 0; t < KCHUNKS; ++t) {
        __syncthreads();                  // previous chunk's ds_reads done
        // stage 80 rows x 128 k: 10 float4/thread in 2 batches of 5
        #pragma unroll
        for (int b = 0; b < 2; ++b) {
            float4 xv[5];
            #pragma unroll
            for (int it = 0; it < 5; ++it) {
                int p   = tid + (b * 5 + it) * 256;   // 0..2559
                int row = p >> 5;                     // 0..79 (32 f4/row)
                int c4  = (p & 31) << 2;              // col 0,4,...,124
                xv[it] = *reinterpret_cast<const float4*>(
                    x + (size_t)(m0 + row) * D + t * BK + c4);
            }
            #pragma unroll
            for (int it = 0; it < 5; ++it) {
                int p   = tid + (b * 5 + it) * 256;
                int row = p >> 5;
                int c4  = (p & 31) << 2;
                u16x4 hh, ll;
                #pragma unroll
                for (int e = 0; e < 4; ++e) {
                    float xe = (e == 0) ? xv[it].x : (e == 1) ? xv[it].y : (e == 2) ? xv[it].z : xv[it].w;
                    _Float16 h = (_Float16)xe;
                    float rl = (xe - (float)h) * 2048.0f;
                    _Float16 l = (_Float16)rl;
                    hh[e] = __builtin_bit_cast(unsigned short, h);
                    ll[e] = __builtin_bit_cast(unsigned short, l);
                }
                int ro = row * ASTR + c4;
                *reinterpret_cast<u16x4*>(AhS + ro) = hh;
                *reinterpret_cast<u16x4*>(AlS + ro) = ll;
            }
        }
        __syncthreads();                  // staging visible to all waves

        // MFMA phase: 4 ks-steps of K=32
        #pragma unroll
        for (int ks = 0; ks < 4; ++ks) {
            f16x8 wfh[3], wfl[3];
            #pragma unroll
            for (int nt = 0; nt < 3; ++nt) {
                int n = nbase + nt * 16 + arow;
                size_t off = (size_t)n * D + t * BK + ks * 32 + apart * 8;
                wfh[nt] = *reinterpret_cast<const f16x8*>(wth + off);
                wfl[nt] = *reinterpret_cast<const f16x8*>(wtl + off);
            }
            #pragma unroll
            for (int mt = 0; mt < 5; ++mt) {
                int ab = (mt * 16 + arow) * (ASTR * 2) + (ks * 4 + apart) * 16;
                f16x8 ah = *reinterpret_cast<const f16x8*>((char*)AhS + ab);
                f16x8 al = *reinterpret_cast<const f16x8*>((char*)AlS + ab);
                #pragma unroll
                for (int nt = 0; nt < 3; ++nt) {
                    acc[mt][nt] = __builtin_amdgcn_mfma_f32_16x16x32_f16(ah, wfh[nt], acc[mt][nt], 0, 0, 0);
                    f32x4 tt = {0.f, 0.f, 0.f, 0.f};
                    tt = __builtin_amdgcn_mfma_f32_16x16x32_f16(ah, wfl[nt], tt, 0, 0, 0);
                    tt = __builtin_amdgcn_mfma_f32_16x16x32_f16(al, wfh[nt], tt, 0, 0, 0);
                    #pragma unroll
                    for (int c = 0; c < 4; ++c)
                        acc[mt][nt][c] = fmaf(tt[c], SCL, acc[mt][nt][c]);
                }
            }
        }
    }
    __syncthreads();

    // ---------- epilogue: two-phase (kq -> scores -> v overlay -> PV) ----------
    // phase 1: dump k,q columns (col < 128)
    #pragma unroll
    for (int mt = 0; mt < 5; ++mt) {
        #pragma unroll
        for (int r = 0; r < 4; ++r) {
            int row = mt * 16 + R[r];
            #pragma unroll
            for (int nt = 0; nt < 3; ++nt) {
                int colbase = nbase + nt * 16;
                if (colbase < 128)
                    kq[row * KQSTR + colbase + Cc[r]] = acc[mt][nt][r];
            }
        }
    }
    __syncthreads();

    // phase 2: masked scores for both batches of this wave (f64 dots, f32 store)
    float* sc0 = scw + wave * 220;
    #pragma unroll
    for (int bb = 0; bb < 2; ++bb) {
        const int r0 = (wave * 2 + bb) * 10;
        float* sc = sc0 + bb * 110;
        #pragma unroll
        for (int it = 0; it < 2; ++it) {
            int p = it * 64 + lane;
            if (p < 100) {
                int i = p / 10;
                int j = p - i * 10;
                double s = 0.0;
                #pragma unroll 8
                for (int c = 0; c < 64; ++c)
                    s += (double)kq[(r0 + i) * KQSTR + c] *
                         (double)kq[(r0 + j) * KQSTR + 64 + c];
                double lim = (j <= i) ? 1e5 : -1e5;
                sc[i * 11 + j] = (float)fmin(s, lim);
            }
        }
    }
    __syncthreads();   // kq reads done -> safe to overlay v

    // phase 3: softmax (lanes 0-9, f64 from f32 scores) + v dump (cols >= 128)
    if (lane < 10) {
        int i = lane;
        #pragma unroll
        for (int bb = 0; bb < 2; ++bb) {
            float* sc = sc0 + bb * 110;
            double vals[10];
            double mx = -1e300;
            #pragma unroll
            for (int j = 0; j < 10; ++j) { vals[j] = (double)sc[i * 11 + j]; mx = fmax(mx, vals[j]); }
            double sum = 0.0;
            #pragma unroll
            for (int j = 0; j < 10; ++j) { vals[j] = exp(vals[j] - mx); sum += vals[j]; }
            double inv = 1.0 / sum;
            #pragma unroll
            for (int j = 0; j < 10; ++j) sc[i * 11 + j] = (float)(vals[j] * inv);
        }
    }
    #pragma unroll
    for (int mt = 0; mt < 5; ++mt) {
        #pragma unroll
        for (int r = 0; r < 4; ++r) {
            int row = mt * 16 + R[r];
            #pragma unroll
            for (int nt = 0; nt < 3; ++nt) {
                int colbase = nbase + nt * 16;
                if (colbase >= 128)
                    vv[row * VSTR + (colbase - 128) + Cc[r]] = acc[mt][nt][r];
            }
        }
    }
    __syncthreads();

    // phase 4: PV (f64 accum, f32 probs/v) + f32 store; lane = output column
    #pragma unroll
    for (int bb = 0; bb < 2; ++bb) {
        const int bloc = wave * 2 + bb;
        const int r0   = bloc * 10;
        float* sc = sc0 + bb * 110;
        size_t ob = (size_t)(blockIdx.x * 8 + bloc) * 640;
        #pragma unroll
        for (int i = 0; i < 10; ++i) {
            double o = 0.0;
            #pragma unroll
            for (int j = 0; j < 10; ++j)
                o += (double)sc[i * 11 + j] * (double)vv[(r0 + j) * VSTR + lane];
            out[ob + (size_t)i * 64 + lane] = (float)o;
        }
    }
}

extern "C" void kernel_launch(void* const* d_in, const int* in_sizes, int n_in,
                              void* d_out, int out_size, void* d_ws, size_t ws_size,
                              hipStream_t stream) {
    const float* x  = (const float*)d_in[0];
    const float* wk = (const float*)d_in[1];
    const float* wq = (const float*)d_in[2];
    const float* wv = (const float*)d_in[3];
    unsigned short* wth = (unsigned short*)d_ws;          // 2 x 192*1024 fp16
    unsigned short* wtl = wth + 192 * 1024;
    float* outp = (float*)d_out;                          // FLOAT32 output

    prep_w<<<768, 256, 0, stream>>>(wk, wq, wv, wth, wtl);
    fused_attn<<<2048, 256, 0, stream>>>(x, wth, wtl, outp);
}